// Round 4
// baseline (1155.187 us; speedup 1.0000x reference)
//
#include <hip/hip_runtime.h>

// Shapes (fixed by the problem)
#define Bx 16
#define Cx 256
#define Dx 32
#define Nx 2304   // 48*48
#define WROWS 320 // 32 q + 32 k + 256 v output rows

typedef _Float16 f16;
typedef _Float16 f16x4 __attribute__((ext_vector_type(4)));
typedef _Float16 f16x8 __attribute__((ext_vector_type(8)));
typedef float    f32x4 __attribute__((ext_vector_type(4)));
typedef float    f32x16 __attribute__((ext_vector_type(16)));

// gfx950 fragment layouts (verified by passing R3):
//  32x32x16_f16: lane holds A[m=lane%32][k=(lane/32)*8 + 0..7]  (f16x8), same for B cols
//  32x32x8_f16 : lane holds A[m=lane%32][k=(lane/32)*4 + 0..3]  (f16x4)
//  C/D 32x32   : col=lane&31, row=(reg&3)+8*(reg>>2)+4*(lane>>5)
#define MFMA_K16(a, b, c) __builtin_amdgcn_mfma_f32_32x32x16_f16((a), (b), (c), 0, 0, 0)
#define MFMA_K8(a, b, c)  __builtin_amdgcn_mfma_f32_32x32x8f16((a), (b), (c), 0, 0, 0)

// ---------------------------------------------------------------------------
// Kernel 0: split W = [Wq; Wk; Wv] (320x256 fp32) into f16 hi/lo, row-major.
// grid 320 x 256 threads, one element each.
// ---------------------------------------------------------------------------
__global__ __launch_bounds__(256) void w_split(
    const float* __restrict__ Wq, const float* __restrict__ Wk,
    const float* __restrict__ Wv, f16* __restrict__ whi, f16* __restrict__ wlo) {
    int idx = blockIdx.x * 256 + threadIdx.x;   // 0..81919
    int row = idx >> 8, k = idx & 255;
    float v = row < 32 ? Wq[row * 256 + k]
            : row < 64 ? Wk[(row - 32) * 256 + k]
                       : Wv[(row - 64) * 256 + k];
    f16 h = (f16)v;
    whi[idx] = h;
    wlo[idx] = (f16)(v - (float)h);
}

// ---------------------------------------------------------------------------
// Kernel 1: fused q/k/v projection via triple-precision MFMA.
// Block = (b, n-tile of 32), 256 threads (4 waves). x tile (256 k x 32 n)
// staged hi/lo in LDS transposed to [n][k] (stride 264 f16: 16B-aligned rows).
// Wave w owns row-tiles {w, w+4, w+8<10}. K-loop: 16 steps x 3 MFMAs/rt.
// Outputs: q,k as [b][n][d] f16 hi/lo; v as [b][c][n] f16 hi/lo.
// grid: Bx * 72 = 1152 blocks.
// ---------------------------------------------------------------------------
__global__ __launch_bounds__(256) void proj(
    const float* __restrict__ x,
    const f16* __restrict__ whi, const f16* __restrict__ wlo,
    const float* __restrict__ bq, const float* __restrict__ bk,
    const float* __restrict__ bv,
    f16* __restrict__ qhi, f16* __restrict__ qlo,
    f16* __restrict__ khi, f16* __restrict__ klo,
    f16* __restrict__ vhi, f16* __restrict__ vlo) {
    __shared__ f16 xh[32 * 264], xl[32 * 264];   // 33792 B total
    int nt = blockIdx.x % 72;
    int b  = blockIdx.x / 72;
    int n0 = nt * 32;
    int t  = threadIdx.x;

    // ---- stage x[256 c][32 n] -> LDS [n][c] hi/lo, split on the fly ----
#pragma unroll
    for (int rr = 0; rr < 8; ++rr) {
        int c  = rr * 32 + (t >> 3);
        int nn = (t & 7) * 4;
        f32x4 v = *(const f32x4*)(x + ((size_t)b * Cx + c) * Nx + n0 + nn);
#pragma unroll
        for (int i = 0; i < 4; ++i) {
            f16 h = (f16)v[i];
            xh[(nn + i) * 264 + c] = h;
            xl[(nn + i) * 264 + c] = (f16)(v[i] - (float)h);
        }
    }
    __syncthreads();

    int w = t >> 6, l = t & 63, il = l & 31, h = l >> 5;
    int nrt = (w < 2) ? 3 : 2;

    f32x16 acc[3] = {};
    for (int s = 0; s < 16; ++s) {
        f16x8 bh = *(const f16x8*)&xh[il * 264 + s * 16 + h * 8];
        f16x8 bl = *(const f16x8*)&xl[il * 264 + s * 16 + h * 8];
        for (int rti = 0; rti < nrt; ++rti) {
            int row0 = (w + 4 * rti) * 32;
            size_t aoff = (size_t)(row0 + il) * 256 + s * 16 + h * 8;
            f16x8 ah = *(const f16x8*)(whi + aoff);
            f16x8 al = *(const f16x8*)(wlo + aoff);
            acc[rti] = MFMA_K16(ah, bh, acc[rti]);
            acc[rti] = MFMA_K16(ah, bl, acc[rti]);
            acc[rti] = MFMA_K16(al, bh, acc[rti]);
        }
    }

    // ---- epilogue: bias add, hi/lo split, store ----
    for (int rti = 0; rti < nrt; ++rti) {
        int rt = w + 4 * rti;
        if (rt < 2) {   // q or k rows -> [b][n][d], 4x f16x4 stores each
            f16* dh = rt ? khi : qhi;
            f16* dl = rt ? klo : qlo;
            const float* bp = rt ? bk : bq;
            size_t nb = ((size_t)b * Nx + n0 + il) * Dx;
#pragma unroll
            for (int g = 0; g < 4; ++g) {
                f16x4 h4, l4;
#pragma unroll
                for (int rr = 0; rr < 4; ++rr) {
                    int d = rr + 8 * g + 4 * h;
                    float v = acc[rti][4 * g + rr] + bp[d];
                    f16 hh = (f16)v;
                    h4[rr] = hh;
                    l4[rr] = (f16)(v - (float)hh);
                }
                *(f16x4*)(dh + nb + 8 * g + 4 * h) = h4;
                *(f16x4*)(dl + nb + 8 * g + 4 * h) = l4;
            }
        } else {        // v rows -> [b][c][n], b16 stores (32 lanes coalesced)
#pragma unroll
            for (int r = 0; r < 16; ++r) {
                int c = (rt - 2) * 32 + (r & 3) + 8 * (r >> 2) + 4 * h;
                float v = acc[rti][r] + bv[c];
                f16 hh = (f16)v;
                size_t o = ((size_t)b * Cx + c) * Nx + n0 + il;
                vhi[o] = hh;
                vlo[o] = (f16)(v - (float)hh);
            }
        }
    }
}

// ---------------------------------------------------------------------------
// Kernel 2: softmax column sums via E^T MFMA, 2-way i-split partials.
// s2[isp][b][j] = sum_{i in half isp} exp(E[i,j]).
// grid: Bx * 72 * 2 = 2304 blocks, 64 threads.
// ---------------------------------------------------------------------------
__global__ __launch_bounds__(64, 4) void col_stats(
    const f16* __restrict__ qhi, const f16* __restrict__ qlo,
    const f16* __restrict__ khi, const f16* __restrict__ klo,
    float* __restrict__ s2) {
    int blk = blockIdx.x;
    int isp = blk & 1; blk >>= 1;
    int jt = blk % 72;
    int b  = blk / 72;
    int j0 = jt * 32;
    int t  = threadIdx.x, il = t & 31, h = t >> 5;

    f16x8 kh[2], kl[2];
#pragma unroll
    for (int ks = 0; ks < 2; ++ks) {
        size_t off = ((size_t)b * Nx + j0 + il) * Dx + h * 8 + ks * 16;
        kh[ks] = *(const f16x8*)(khi + off);
        kl[ks] = *(const f16x8*)(klo + off);
    }
    f32x16 sacc = {};
    for (int it = isp * 36; it < isp * 36 + 36; ++it) {
        f16x8 qh[2], ql[2];
#pragma unroll
        for (int ks = 0; ks < 2; ++ks) {
            size_t off = ((size_t)b * Nx + it * 32 + il) * Dx + h * 8 + ks * 16;
            qh[ks] = *(const f16x8*)(qhi + off);
            ql[ks] = *(const f16x8*)(qlo + off);
        }
        f32x16 e = {};
        e = MFMA_K16(kh[0], qh[0], e);
        e = MFMA_K16(kh[0], ql[0], e);
        e = MFMA_K16(kl[0], qh[0], e);
        e = MFMA_K16(kh[1], qh[1], e);
        e = MFMA_K16(kh[1], ql[1], e);
        e = MFMA_K16(kl[1], qh[1], e);
#pragma unroll
        for (int r = 0; r < 16; ++r) sacc[r] += __expf(e[r]);
    }
#pragma unroll
    for (int r = 0; r < 16; ++r) {
        float v = sacc[r];
        for (int msk = 1; msk <= 16; msk <<= 1) v += __shfl_xor(v, msk);
        if (il == 0)
            s2[(size_t)isp * Bx * Nx + (size_t)b * Nx + j0 + (r & 3) + 8 * (r >> 2) + 4 * h] = v;
    }
}

// ---------------------------------------------------------------------------
// Kernel 3: main. One wave per (b, i-32 tile, c-64 quarter). Barrier-free
// j-loop; E^T C-regs feed PV B-operand in registers. D = out^T -> coalesced.
// grid: Bx * 72 * 4 = 4608 blocks, 64 threads -> 18 waves/CU.
// ---------------------------------------------------------------------------
__global__ __launch_bounds__(64, 4) void attn_out(
    const f16* __restrict__ qhi, const f16* __restrict__ qlo,
    const f16* __restrict__ khi, const f16* __restrict__ klo,
    const f16* __restrict__ vhi, const f16* __restrict__ vlo,
    const float* __restrict__ s2, const float* __restrict__ x,
    const float* __restrict__ gamma, float* __restrict__ out) {
    __shared__ float rs[Nx];   // 9216 B
    int blk = blockIdx.x;
    int w  = blk & 3;  blk >>= 2;
    int it = blk % 72;
    int b  = blk / 72;
    int i0 = it * 32;
    int c0 = w * 64;
    int t = threadIdx.x, il = t & 31, h = t >> 5;

    {   // rs[j] = 1 / (s_half0[j] + s_half1[j])
        const f32x4* sa = (const f32x4*)(s2 + (size_t)b * Nx);
        const f32x4* sb = (const f32x4*)(s2 + (size_t)Bx * Nx + (size_t)b * Nx);
        f32x4* rs4 = (f32x4*)rs;
        for (int r = t; r < Nx / 4; r += 64) {
            f32x4 va = sa[r], vb = sb[r];
            rs4[r] = (f32x4){1.0f / (va[0] + vb[0]), 1.0f / (va[1] + vb[1]),
                             1.0f / (va[2] + vb[2]), 1.0f / (va[3] + vb[3])};
        }
    }
    __syncthreads();

    // Q as B-operand for E^T (hoisted)
    f16x8 qh[2], ql[2];
#pragma unroll
    for (int ks = 0; ks < 2; ++ks) {
        size_t off = ((size_t)b * Nx + i0 + il) * Dx + h * 8 + ks * 16;
        qh[ks] = *(const f16x8*)(qhi + off);
        ql[ks] = *(const f16x8*)(qlo + off);
    }

    f32x16 acc[2] = {};
    const f16* vbh = vhi + ((size_t)b * Cx + c0) * Nx;
    const f16* vbl = vlo + ((size_t)b * Cx + c0) * Nx;

    for (int jt = 0; jt < 72; ++jt) {
        int j0 = jt * 32;
        f16x8 kh[2], kl[2];
#pragma unroll
        for (int ks = 0; ks < 2; ++ks) {
            size_t off = ((size_t)b * Nx + j0 + il) * Dx + h * 8 + ks * 16;
            kh[ks] = *(const f16x8*)(khi + off);
            kl[ks] = *(const f16x8*)(klo + off);
        }
        f16x4 vh[2][4], vl[2][4];
#pragma unroll
        for (int cg = 0; cg < 2; ++cg)
#pragma unroll
            for (int g = 0; g < 4; ++g) {
                size_t voff = (size_t)(cg * 32 + il) * Nx + j0 + g * 8 + h * 4;
                vh[cg][g] = *(const f16x4*)(vbh + voff);
                vl[cg][g] = *(const f16x4*)(vbl + voff);
            }
        // ---- E^T tile (rows j, cols i) ----
        f32x16 e = {};
        e = MFMA_K16(kh[0], qh[0], e);
        e = MFMA_K16(kh[0], ql[0], e);
        e = MFMA_K16(kl[0], qh[0], e);
        e = MFMA_K16(kh[1], qh[1], e);
        e = MFMA_K16(kh[1], ql[1], e);
        e = MFMA_K16(kl[1], qh[1], e);
        // ---- P^T = exp(E^T)*rs[j], split; C-regs 4g..4g+3 = B-frag block g ----
        f16x4 ph[4], pl[4];
#pragma unroll
        for (int g = 0; g < 4; ++g)
#pragma unroll
            for (int jj = 0; jj < 4; ++jj) {
                float p = __expf(e[4 * g + jj]) * rs[j0 + jj + 8 * g + 4 * h];
                f16 hh = (f16)p;
                ph[g][jj] = hh;
                pl[g][jj] = (f16)(p - (float)hh);
            }
        // ---- PV ----
#pragma unroll
        for (int cg = 0; cg < 2; ++cg)
#pragma unroll
            for (int g = 0; g < 4; ++g) {
                acc[cg] = MFMA_K8(vh[cg][g], ph[g], acc[cg]);
                acc[cg] = MFMA_K8(vh[cg][g], pl[g], acc[cg]);
                acc[cg] = MFMA_K8(vl[cg][g], ph[g], acc[cg]);
            }
    }

    // ---- epilogue: D rows = c, cols = i -> coalesced b32 stores ----
    float gm = gamma[0];
#pragma unroll
    for (int cg = 0; cg < 2; ++cg)
#pragma unroll
        for (int r = 0; r < 16; ++r) {
            int c = c0 + cg * 32 + (r & 3) + 8 * (r >> 2) + 4 * h;
            int i = i0 + il;
            size_t idx = ((size_t)b * Cx + c) * Nx + i;
            out[idx] = x[idx] + gm * acc[cg][r];
        }
}

// ---------------------------------------------------------------------------
extern "C" void kernel_launch(void* const* d_in, const int* in_sizes, int n_in,
                              void* d_out, int out_size, void* d_ws, size_t ws_size,
                              hipStream_t stream) {
    const float* x     = (const float*)d_in[0];
    const float* Wq    = (const float*)d_in[1];
    const float* bq    = (const float*)d_in[2];
    const float* Wk    = (const float*)d_in[3];
    const float* bk    = (const float*)d_in[4];
    const float* Wv    = (const float*)d_in[5];
    const float* bv    = (const float*)d_in[6];
    const float* gamma = (const float*)d_in[7];
    float* out = (float*)d_out;

    // ws layout (~47.8 MB):
    const size_t QK  = (size_t)Bx * Nx * Dx;   // 1.18M f16 each
    const size_t VN  = (size_t)Bx * Cx * Nx;   // 9.44M f16 each
    const size_t WSZ = (size_t)WROWS * Cx;     // 82K f16 each
    f16* qhi = (f16*)d_ws;
    f16* qlo = qhi + QK;
    f16* khi = qlo + QK;
    f16* klo = khi + QK;
    f16* vhi = klo + QK;
    f16* vlo = vhi + VN;
    f16* whi = vlo + VN;
    f16* wlo = whi + WSZ;
    float* s2 = (float*)(wlo + WSZ);           // [2][Bx][Nx]

    w_split  <<<WROWS,       256, 0, stream>>>(Wq, Wk, Wv, whi, wlo);
    proj     <<<Bx * 72,     256, 0, stream>>>(x, whi, wlo, bq, bk, bv,
                                               qhi, qlo, khi, klo, vhi, vlo);
    col_stats<<<Bx * 72 * 2, 64,  0, stream>>>(qhi, qlo, khi, klo, s2);
    attn_out <<<Bx * 72 * 4, 64,  0, stream>>>(qhi, qlo, khi, klo, vhi, vlo,
                                               s2, x, gamma, out);
}

// Round 5
// 838.455 us; speedup vs baseline: 1.3778x; 1.3778x over previous
//
#include <hip/hip_runtime.h>

// Shapes (fixed by the problem)
#define Bx 16
#define Cx 256
#define Dx 32
#define Nx 2304   // 48*48
#define WROWS 320 // 32 q + 32 k + 256 v output rows

typedef _Float16 f16;
typedef _Float16 f16x4 __attribute__((ext_vector_type(4)));
typedef _Float16 f16x8 __attribute__((ext_vector_type(8)));
typedef float    f32x4 __attribute__((ext_vector_type(4)));
typedef float    f32x16 __attribute__((ext_vector_type(16)));

// gfx950 fragment layouts (verified by passing R3/R4):
//  32x32x16_f16: lane holds A[m=lane%32][k=(lane/32)*8 + 0..7]  (f16x8), B same
//  32x32x8_f16 : lane holds A[m=lane%32][k=(lane/32)*4 + 0..3]  (f16x4)
//  C/D 32x32   : col=lane&31, row=(reg&3)+8*(reg>>2)+4*(lane>>5)
#define MFMA_K16(a, b, c) __builtin_amdgcn_mfma_f32_32x32x16_f16((a), (b), (c), 0, 0, 0)
#define MFMA_K8(a, b, c)  __builtin_amdgcn_mfma_f32_32x32x8f16((a), (b), (c), 0, 0, 0)

// ---------------------------------------------------------------------------
// Kernel 0: split W = [Wq; Wk; Wv] (320x256 fp32) into f16 hi/lo, row-major.
// ---------------------------------------------------------------------------
__global__ __launch_bounds__(256) void w_split(
    const float* __restrict__ Wq, const float* __restrict__ Wk,
    const float* __restrict__ Wv, f16* __restrict__ whi, f16* __restrict__ wlo) {
    int idx = blockIdx.x * 256 + threadIdx.x;   // 0..81919
    int row = idx >> 8, k = idx & 255;
    float v = row < 32 ? Wq[row * 256 + k]
            : row < 64 ? Wk[(row - 32) * 256 + k]
                       : Wv[(row - 64) * 256 + k];
    f16 h = (f16)v;
    whi[idx] = h;
    wlo[idx] = (f16)(v - (float)h);
}

// ---------------------------------------------------------------------------
// Kernel 1: fused q/k/v projection via triple-precision MFMA (passed R4).
// XCD-swizzled: batch-pair per XCD so q/k/v writes land in the local L2.
// grid: Bx * 72 = 1152 blocks, 256 threads.
// ---------------------------------------------------------------------------
__global__ __launch_bounds__(256) void proj(
    const float* __restrict__ x,
    const f16* __restrict__ whi, const f16* __restrict__ wlo,
    const float* __restrict__ bq, const float* __restrict__ bk,
    const float* __restrict__ bv,
    f16* __restrict__ qhi, f16* __restrict__ qlo,
    f16* __restrict__ khi, f16* __restrict__ klo,
    f16* __restrict__ vhi, f16* __restrict__ vlo) {
    __shared__ f16 xh[32 * 264], xl[32 * 264];   // 33792 B total
    int xcd = blockIdx.x & 7;
    int u   = blockIdx.x >> 3;          // 0..143
    int b   = (xcd << 1) | (u & 1);
    int nt  = u >> 1;                   // 0..71
    int n0 = nt * 32;
    int t  = threadIdx.x;

    // ---- stage x[256 c][32 n] -> LDS [n][c] hi/lo, split on the fly ----
#pragma unroll
    for (int rr = 0; rr < 8; ++rr) {
        int c  = rr * 32 + (t >> 3);
        int nn = (t & 7) * 4;
        f32x4 v = *(const f32x4*)(x + ((size_t)b * Cx + c) * Nx + n0 + nn);
#pragma unroll
        for (int i = 0; i < 4; ++i) {
            f16 h = (f16)v[i];
            xh[(nn + i) * 264 + c] = h;
            xl[(nn + i) * 264 + c] = (f16)(v[i] - (float)h);
        }
    }
    __syncthreads();

    int w = t >> 6, l = t & 63, il = l & 31, h = l >> 5;
    int nrt = (w < 2) ? 3 : 2;

    f32x16 acc[3] = {};
    for (int s = 0; s < 16; ++s) {
        f16x8 bh = *(const f16x8*)&xh[il * 264 + s * 16 + h * 8];
        f16x8 bl = *(const f16x8*)&xl[il * 264 + s * 16 + h * 8];
        for (int rti = 0; rti < nrt; ++rti) {
            int row0 = (w + 4 * rti) * 32;
            size_t aoff = (size_t)(row0 + il) * 256 + s * 16 + h * 8;
            f16x8 ah = *(const f16x8*)(whi + aoff);
            f16x8 al = *(const f16x8*)(wlo + aoff);
            acc[rti] = MFMA_K16(ah, bh, acc[rti]);
            acc[rti] = MFMA_K16(ah, bl, acc[rti]);
            acc[rti] = MFMA_K16(al, bh, acc[rti]);
        }
    }

    // ---- epilogue: bias add, hi/lo split, store ----
    for (int rti = 0; rti < nrt; ++rti) {
        int rt = w + 4 * rti;
        if (rt < 2) {   // q or k rows -> [b][n][d]
            f16* dh = rt ? khi : qhi;
            f16* dl = rt ? klo : qlo;
            const float* bp = rt ? bk : bq;
            size_t nb = ((size_t)b * Nx + n0 + il) * Dx;
#pragma unroll
            for (int g = 0; g < 4; ++g) {
                f16x4 h4, l4;
#pragma unroll
                for (int rr = 0; rr < 4; ++rr) {
                    int d = rr + 8 * g + 4 * h;
                    float v = acc[rti][4 * g + rr] + bp[d];
                    f16 hh = (f16)v;
                    h4[rr] = hh;
                    l4[rr] = (f16)(v - (float)hh);
                }
                *(f16x4*)(dh + nb + 8 * g + 4 * h) = h4;
                *(f16x4*)(dl + nb + 8 * g + 4 * h) = l4;
            }
        } else {        // v rows -> [b][c][n]
#pragma unroll
            for (int r = 0; r < 16; ++r) {
                int c = (rt - 2) * 32 + (r & 3) + 8 * (r >> 2) + 4 * h;
                float v = acc[rti][r] + bv[c];
                f16 hh = (f16)v;
                size_t o = ((size_t)b * Cx + c) * Nx + n0 + il;
                vhi[o] = hh;
                vlo[o] = (f16)(v - (float)hh);
            }
        }
    }
}

// ---------------------------------------------------------------------------
// Kernel 2: softmax column sums via E^T MFMA, 2-way i-split partials.
// XCD-swizzled + one-step-ahead Q prefetch (register double buffer).
// grid: Bx * 72 * 2 = 2304 blocks, 64 threads.
// ---------------------------------------------------------------------------
__global__ __launch_bounds__(64, 4) void col_stats(
    const f16* __restrict__ qhi, const f16* __restrict__ qlo,
    const f16* __restrict__ khi, const f16* __restrict__ klo,
    float* __restrict__ s2) {
    int xcd = blockIdx.x & 7;
    int u   = blockIdx.x >> 3;          // 0..287
    int b   = (xcd << 1) | (u & 1);
    int u2  = u >> 1;                   // 0..143
    int jt  = u2 % 72;
    int isp = u2 / 72;
    int j0 = jt * 32;
    int t  = threadIdx.x, il = t & 31, h = t >> 5;

    f16x8 kh[2], kl[2];
#pragma unroll
    for (int ks = 0; ks < 2; ++ks) {
        size_t off = ((size_t)b * Nx + j0 + il) * Dx + h * 8 + ks * 16;
        kh[ks] = *(const f16x8*)(khi + off);
        kl[ks] = *(const f16x8*)(klo + off);
    }
    int it0 = isp * 36;
    f16x8 qhA[2], qlA[2], qhB[2], qlB[2];
    f32x16 sacc = {};

#define LOADQ(QH, QL, IT) do {                                                \
        size_t _o0 = ((size_t)b * Nx + (IT) * 32 + il) * Dx + h * 8;          \
        QH[0] = *(const f16x8*)(qhi + _o0);                                   \
        QL[0] = *(const f16x8*)(qlo + _o0);                                   \
        QH[1] = *(const f16x8*)(qhi + _o0 + 16);                              \
        QL[1] = *(const f16x8*)(qlo + _o0 + 16);                              \
    } while (0)
#define CSTEP(QH, QL) do {                                                    \
        f32x16 e = {};                                                        \
        e = MFMA_K16(kh[0], QH[0], e);                                        \
        e = MFMA_K16(kh[0], QL[0], e);                                        \
        e = MFMA_K16(kl[0], QH[0], e);                                        \
        e = MFMA_K16(kh[1], QH[1], e);                                        \
        e = MFMA_K16(kh[1], QL[1], e);                                        \
        e = MFMA_K16(kl[1], QH[1], e);                                        \
        _Pragma("unroll")                                                     \
        for (int r = 0; r < 16; ++r) sacc[r] += __expf(e[r]);                 \
    } while (0)

    LOADQ(qhA, qlA, it0);
    for (int it = it0; it < it0 + 36; it += 2) {
        LOADQ(qhB, qlB, it + 1);
        CSTEP(qhA, qlA);
        if (it + 2 < it0 + 36) LOADQ(qhA, qlA, it + 2);
        CSTEP(qhB, qlB);
    }
#undef LOADQ
#undef CSTEP

#pragma unroll
    for (int r = 0; r < 16; ++r) {
        float v = sacc[r];
        for (int msk = 1; msk <= 16; msk <<= 1) v += __shfl_xor(v, msk);
        if (il == 0)
            s2[(size_t)isp * Bx * Nx + (size_t)b * Nx + j0 + (r & 3) + 8 * (r >> 2) + 4 * h] = v;
    }
}

// ---------------------------------------------------------------------------
// Kernel 3: main. One wave per (b, i-64 tile, c-64 quarter) — R3 tiling
// (traffic-optimal) + XCD swizzle + one-jt-ahead K/V register prefetch.
// Barrier-free j-loop; E^T C-regs feed PV B-operand in registers.
// grid: Bx * 36 * 4 = 2304 blocks, 64 threads.
// ---------------------------------------------------------------------------
__global__ __launch_bounds__(64, 2) void attn_out(
    const f16* __restrict__ qhi, const f16* __restrict__ qlo,
    const f16* __restrict__ khi, const f16* __restrict__ klo,
    const f16* __restrict__ vhi, const f16* __restrict__ vlo,
    const float* __restrict__ s2, const float* __restrict__ x,
    const float* __restrict__ gamma, float* __restrict__ out) {
    __shared__ float rs[Nx];   // 9216 B
    int xcd = blockIdx.x & 7;
    int u   = blockIdx.x >> 3;          // 0..287
    int b   = (xcd << 1) | (u & 1);
    int u2  = u >> 1;                   // 0..143
    int it64 = u2 % 36;
    int w    = u2 / 36;                 // c-quarter
    int i0 = it64 * 64;
    int c0 = w * 64;
    int t = threadIdx.x, il = t & 31, h = t >> 5;

    {   // rs[j] = 1 / (s_half0[j] + s_half1[j])
        const f32x4* sa = (const f32x4*)(s2 + (size_t)b * Nx);
        const f32x4* sb = (const f32x4*)(s2 + (size_t)Bx * Nx + (size_t)b * Nx);
        f32x4* rs4 = (f32x4*)rs;
        for (int r = t; r < Nx / 4; r += 64) {
            f32x4 va = sa[r], vb = sb[r];
            rs4[r] = (f32x4){1.0f / (va[0] + vb[0]), 1.0f / (va[1] + vb[1]),
                             1.0f / (va[2] + vb[2]), 1.0f / (va[3] + vb[3])};
        }
    }
    __syncthreads();

    // Q as B-operand for E^T, both i-subtiles (resident all loop)
    f16x8 qh[2][2], ql[2][2];   // [itile][ks]
#pragma unroll
    for (int itile = 0; itile < 2; ++itile)
#pragma unroll
        for (int ks = 0; ks < 2; ++ks) {
            size_t off = ((size_t)b * Nx + i0 + itile * 32 + il) * Dx + h * 8 + ks * 16;
            qh[itile][ks] = *(const f16x8*)(qhi + off);
            ql[itile][ks] = *(const f16x8*)(qlo + off);
        }

    f32x16 acc[2][2] = {};   // [itile][cg] : out^T tile [c 32][i 32]
    const f16* vbh = vhi + ((size_t)b * Cx + c0) * Nx;
    const f16* vbl = vlo + ((size_t)b * Cx + c0) * Nx;

    // double-buffered K/V fragments
    f16x8 khA[2], klA[2], khB[2], klB[2];
    f16x4 vhA[2][4], vlA[2][4], vhB[2][4], vlB[2][4];

#define LOADKV(KH, KL, VH, VL, J0) do {                                       \
        _Pragma("unroll")                                                     \
        for (int ks = 0; ks < 2; ++ks) {                                      \
            size_t _o = ((size_t)b * Nx + (J0) + il) * Dx + h * 8 + ks * 16;  \
            KH[ks] = *(const f16x8*)(khi + _o);                               \
            KL[ks] = *(const f16x8*)(klo + _o);                               \
        }                                                                     \
        _Pragma("unroll")                                                     \
        for (int cg = 0; cg < 2; ++cg)                                        \
            _Pragma("unroll")                                                 \
            for (int g = 0; g < 4; ++g) {                                     \
                size_t _vo = (size_t)(cg * 32 + il) * Nx + (J0) + g * 8 + h * 4; \
                VH[cg][g] = *(const f16x4*)(vbh + _vo);                       \
                VL[cg][g] = *(const f16x4*)(vbl + _vo);                       \
            }                                                                 \
    } while (0)

#define ASTEP(KH, KL, VH, VL, J0) do {                                        \
        _Pragma("unroll")                                                     \
        for (int itile = 0; itile < 2; ++itile) {                             \
            f32x16 e = {};                                                    \
            e = MFMA_K16(KH[0], qh[itile][0], e);                             \
            e = MFMA_K16(KH[0], ql[itile][0], e);                             \
            e = MFMA_K16(KL[0], qh[itile][0], e);                             \
            e = MFMA_K16(KH[1], qh[itile][1], e);                             \
            e = MFMA_K16(KH[1], ql[itile][1], e);                             \
            e = MFMA_K16(KL[1], qh[itile][1], e);                             \
            f16x4 ph[4], pl[4];                                               \
            _Pragma("unroll")                                                 \
            for (int g = 0; g < 4; ++g)                                       \
                _Pragma("unroll")                                             \
                for (int jj = 0; jj < 4; ++jj) {                              \
                    float p = __expf(e[4 * g + jj]) * rs[(J0) + jj + 8 * g + 4 * h]; \
                    f16 hh = (f16)p;                                          \
                    ph[g][jj] = hh;                                           \
                    pl[g][jj] = (f16)(p - (float)hh);                         \
                }                                                             \
            _Pragma("unroll")                                                 \
            for (int cg = 0; cg < 2; ++cg)                                    \
                _Pragma("unroll")                                             \
                for (int g = 0; g < 4; ++g) {                                 \
                    acc[itile][cg] = MFMA_K8(VH[cg][g], ph[g], acc[itile][cg]); \
                    acc[itile][cg] = MFMA_K8(VH[cg][g], pl[g], acc[itile][cg]); \
                    acc[itile][cg] = MFMA_K8(VL[cg][g], ph[g], acc[itile][cg]); \
                }                                                             \
        }                                                                     \
    } while (0)

    LOADKV(khA, klA, vhA, vlA, 0);
    for (int jt = 0; jt < 72; jt += 2) {
        LOADKV(khB, klB, vhB, vlB, (jt + 1) * 32);
        ASTEP(khA, klA, vhA, vlA, jt * 32);
        if (jt + 2 < 72) LOADKV(khA, klA, vhA, vlA, (jt + 2) * 32);
        ASTEP(khB, klB, vhB, vlB, (jt + 1) * 32);
    }
#undef LOADKV
#undef ASTEP

    // ---- epilogue: D rows = c, cols = i -> coalesced b32 stores ----
    float gm = gamma[0];
#pragma unroll
    for (int itile = 0; itile < 2; ++itile)
#pragma unroll
        for (int cg = 0; cg < 2; ++cg)
#pragma unroll
            for (int r = 0; r < 16; ++r) {
                int c = c0 + cg * 32 + (r & 3) + 8 * (r >> 2) + 4 * h;
                int i = i0 + itile * 32 + il;
                size_t idx = ((size_t)b * Cx + c) * Nx + i;
                out[idx] = x[idx] + gm * acc[itile][cg][r];
            }
}

// ---------------------------------------------------------------------------
extern "C" void kernel_launch(void* const* d_in, const int* in_sizes, int n_in,
                              void* d_out, int out_size, void* d_ws, size_t ws_size,
                              hipStream_t stream) {
    const float* x     = (const float*)d_in[0];
    const float* Wq    = (const float*)d_in[1];
    const float* bq    = (const float*)d_in[2];
    const float* Wk    = (const float*)d_in[3];
    const float* bk    = (const float*)d_in[4];
    const float* Wv    = (const float*)d_in[5];
    const float* bv    = (const float*)d_in[6];
    const float* gamma = (const float*)d_in[7];
    float* out = (float*)d_out;

    // ws layout (~47.8 MB):
    const size_t QK  = (size_t)Bx * Nx * Dx;
    const size_t VN  = (size_t)Bx * Cx * Nx;
    const size_t WSZ = (size_t)WROWS * Cx;
    f16* qhi = (f16*)d_ws;
    f16* qlo = qhi + QK;
    f16* khi = qlo + QK;
    f16* klo = khi + QK;
    f16* vhi = klo + QK;
    f16* vlo = vhi + VN;
    f16* whi = vlo + VN;
    f16* wlo = whi + WSZ;
    float* s2 = (float*)(wlo + WSZ);           // [2][Bx][Nx]

    w_split  <<<WROWS,       256, 0, stream>>>(Wq, Wk, Wv, whi, wlo);
    proj     <<<Bx * 72,     256, 0, stream>>>(x, whi, wlo, bq, bk, bv,
                                               qhi, qlo, khi, klo, vhi, vlo);
    col_stats<<<Bx * 72 * 2, 64,  0, stream>>>(qhi, qlo, khi, klo, s2);
    attn_out <<<Bx * 36 * 4, 64,  0, stream>>>(qhi, qlo, khi, klo, vhi, vlo,
                                               s2, x, gamma, out);
}